// Round 3
// baseline (456.143 us; speedup 1.0000x reference)
//
#include <hip/hip_runtime.h>
#include <hip/hip_bf16.h>

#define NROWS 262144
#define DIM   256
#define NH    4
#define HD    64
#define NSEG  8192

// workspace layout (floats):
//   vwT : [256][256]  transpose of value_w      offset 0
//   qk  : [4][256]    folded query@key_w        offset 65536
//   qb  : [4]         folded query@key_b        offset 66560
#define WS_QK 65536
#define WS_QB 66560

// ---------------------------------------------------------------------------
// Prep: transpose value_w (64 tile blocks) + fold query into key_w/key_b (1 blk)
// ---------------------------------------------------------------------------
__global__ __launch_bounds__(256) void prep_kernel(
    const float* __restrict__ query,
    const float* __restrict__ key_w,
    const float* __restrict__ key_b,
    const float* __restrict__ value_w,
    float* __restrict__ ws) {
  float* vwT = ws;
  float* qk  = ws + WS_QK;
  float* qb  = ws + WS_QB;
  const int t = threadIdx.x;

  if (blockIdx.x < 64) {
    // 32x32 LDS-tiled transpose of value_w -> vwT[i][r] = value_w[r][i]
    __shared__ float tile[32][33];
    const int bx = (blockIdx.x & 7) * 32;   // column block of value_w
    const int by = (blockIdx.x >> 3) * 32;  // row block of value_w
    const int tx = t & 31, ty = t >> 5;     // ty in 0..7
#pragma unroll
    for (int k = 0; k < 4; ++k)
      tile[ty + 8 * k][tx] = value_w[(by + ty + 8 * k) * DIM + bx + tx];
    __syncthreads();
#pragma unroll
    for (int k = 0; k < 4; ++k)
      vwT[(bx + ty + 8 * k) * DIM + by + tx] = tile[tx][ty + 8 * k];
  } else {
    // qk[h][i] = scale * sum_d query[h][d] * key_w[h*64+d][i]
    const float scale = 0.125f;  // HD^-0.5
#pragma unroll
    for (int h = 0; h < NH; ++h) {
      float acc = 0.f;
      for (int d = 0; d < HD; ++d)
        acc += query[h * HD + d] * key_w[(h * HD + d) * DIM + t];
      qk[h * DIM + t] = acc * scale;
    }
    if (t < NH) {
      float acc = 0.f;
      for (int d = 0; d < HD; ++d)
        acc += query[t * HD + d] * key_b[t * HD + d];
      qb[t] = acc * scale;
    }
  }
}

// ---------------------------------------------------------------------------
// Main: one wave per segment. Stream x once; per row compute 4 head logits
// (wave reduce), exp, accumulate e*x into per-wave z[4][DIM] (regs).
// Epilogue: block-cooperative z @ value_w.T using pre-transposed vwT.
// ---------------------------------------------------------------------------
__global__ __launch_bounds__(256) void main_kernel(
    const float* __restrict__ x,
    const int* __restrict__ batch,
    const float* __restrict__ value_b,
    const float* __restrict__ ws,
    float* __restrict__ out) {
  const float* vwT = ws;
  const float* qk  = ws + WS_QK;
  const float* qb  = ws + WS_QB;

  __shared__ float zu[4][NH][DIM];  // [seg-in-block][head][col], unnormalized
  __shared__ float sSh[4][NH];      // exp-sums

  const int t = threadIdx.x;
  const int w = t >> 6;   // wave id = segment-in-block
  const int l = t & 63;   // lane
  const int b = blockIdx.x * 4 + w;

  // contiguous row range of segment b (batch is sorted)
  int lo = 0, hi = NROWS;
  while (lo < hi) { int mid = (lo + hi) >> 1; if (batch[mid] < b) lo = mid + 1; else hi = mid; }
  const int start = lo;
  hi = NROWS;
  while (lo < hi) { int mid = (lo + hi) >> 1; if (batch[mid] < b + 1) lo = mid + 1; else hi = mid; }
  const int end = lo;

  const float4 q0 = *(const float4*)(qk + 0 * DIM + 4 * l);
  const float4 q1 = *(const float4*)(qk + 1 * DIM + 4 * l);
  const float4 q2 = *(const float4*)(qk + 2 * DIM + 4 * l);
  const float4 q3 = *(const float4*)(qk + 3 * DIM + 4 * l);
  const float qb0 = qb[0], qb1 = qb[1], qb2 = qb[2], qb3 = qb[3];

  float4 z0 = {0.f, 0.f, 0.f, 0.f}, z1 = z0, z2 = z0, z3 = z0;
  float s0 = 0.f, s1 = 0.f, s2 = 0.f, s3 = 0.f;

  for (int n = start; n < end; ++n) {
    const float4 xv = *(const float4*)(x + (size_t)n * DIM + 4 * l);
    float p0 = q0.x * xv.x + q0.y * xv.y + q0.z * xv.z + q0.w * xv.w;
    float p1 = q1.x * xv.x + q1.y * xv.y + q1.z * xv.z + q1.w * xv.w;
    float p2 = q2.x * xv.x + q2.y * xv.y + q2.z * xv.z + q2.w * xv.w;
    float p3 = q3.x * xv.x + q3.y * xv.y + q3.z * xv.z + q3.w * xv.w;
#pragma unroll
    for (int m = 1; m < 64; m <<= 1) {
      p0 += __shfl_xor(p0, m, 64);
      p1 += __shfl_xor(p1, m, 64);
      p2 += __shfl_xor(p2, m, 64);
      p3 += __shfl_xor(p3, m, 64);
    }
    const float e0 = __expf(fminf(fmaxf(p0 + qb0, -20.f), 20.f));
    const float e1 = __expf(fminf(fmaxf(p1 + qb1, -20.f), 20.f));
    const float e2 = __expf(fminf(fmaxf(p2 + qb2, -20.f), 20.f));
    const float e3 = __expf(fminf(fmaxf(p3 + qb3, -20.f), 20.f));
    s0 += e0; s1 += e1; s2 += e2; s3 += e3;
    z0.x += e0 * xv.x; z0.y += e0 * xv.y; z0.z += e0 * xv.z; z0.w += e0 * xv.w;
    z1.x += e1 * xv.x; z1.y += e1 * xv.y; z1.z += e1 * xv.z; z1.w += e1 * xv.w;
    z2.x += e2 * xv.x; z2.y += e2 * xv.y; z2.z += e2 * xv.z; z2.w += e2 * xv.w;
    z3.x += e3 * xv.x; z3.y += e3 * xv.y; z3.z += e3 * xv.z; z3.w += e3 * xv.w;
  }

  *(float4*)&zu[w][0][4 * l] = z0;
  *(float4*)&zu[w][1][4 * l] = z1;
  *(float4*)&zu[w][2][4 * l] = z2;
  *(float4*)&zu[w][3][4 * l] = z3;
  if (l == 0) { sSh[w][0] = s0; sSh[w][1] = s1; sSh[w][2] = s2; sSh[w][3] = s3; }
  __syncthreads();

  // Epilogue: out[b, r] = (1/(s+eps)) * sum_i zu[seg][h][i]*value_w[r][i]
  //                       + (s/(s+eps)) * value_b[r]
  // thread t owns output column r = t (head h = t>>6) for all 4 segments.
  const int h = t >> 6;
  float inv[4], cb[4];
#pragma unroll
  for (int seg = 0; seg < 4; ++seg) {
    const float sv = sSh[seg][h];
    const float iv = 1.f / (sv + 1e-8f);
    inv[seg] = iv;
    cb[seg]  = sv * iv;
  }
  float a0 = 0.f, a1 = 0.f, a2 = 0.f, a3 = 0.f;
  for (int i = 0; i < DIM; i += 4) {
    const float w0 = vwT[(i + 0) * DIM + t];  // = value_w[t][i+0], lane-coalesced
    const float w1 = vwT[(i + 1) * DIM + t];
    const float w2 = vwT[(i + 2) * DIM + t];
    const float w3 = vwT[(i + 3) * DIM + t];
    const float4 za = *(const float4*)&zu[0][h][i];
    const float4 zb = *(const float4*)&zu[1][h][i];
    const float4 zc = *(const float4*)&zu[2][h][i];
    const float4 zd = *(const float4*)&zu[3][h][i];
    a0 += w0 * za.x + w1 * za.y + w2 * za.z + w3 * za.w;
    a1 += w0 * zb.x + w1 * zb.y + w2 * zb.z + w3 * zb.w;
    a2 += w0 * zc.x + w1 * zc.y + w2 * zc.z + w3 * zc.w;
    a3 += w0 * zd.x + w1 * zd.y + w2 * zd.z + w3 * zd.w;
  }
  const float vb = value_b[t];
  const int b0 = blockIdx.x * 4;
  out[(size_t)(b0 + 0) * DIM + t] = a0 * inv[0] + cb[0] * vb;
  out[(size_t)(b0 + 1) * DIM + t] = a1 * inv[1] + cb[1] * vb;
  out[(size_t)(b0 + 2) * DIM + t] = a2 * inv[2] + cb[2] * vb;
  out[(size_t)(b0 + 3) * DIM + t] = a3 * inv[3] + cb[3] * vb;
}

extern "C" void kernel_launch(void* const* d_in, const int* in_sizes, int n_in,
                              void* d_out, int out_size, void* d_ws, size_t ws_size,
                              hipStream_t stream) {
  const float* x       = (const float*)d_in[0];
  const int*   batch   = (const int*)d_in[1];
  const float* query   = (const float*)d_in[2];
  const float* key_w   = (const float*)d_in[3];
  const float* key_b   = (const float*)d_in[4];
  const float* value_w = (const float*)d_in[5];
  const float* value_b = (const float*)d_in[6];
  float* out = (float*)d_out;
  float* ws  = (float*)d_ws;

  prep_kernel<<<65, 256, 0, stream>>>(query, key_w, key_b, value_w, ws);
  main_kernel<<<2048, 256, 0, stream>>>(x, batch, value_b, ws, out);
}

// Round 5
// 415.076 us; speedup vs baseline: 1.0989x; 1.0989x over previous
//
#include <hip/hip_runtime.h>
#include <hip/hip_bf16.h>

#define NROWS 262144
#define DIM   256
#define NH    4
#define HD    64
#define NSEG  8192
#define SPB   8               // segments per block
#define NBLK  (NSEG / SPB)    // 1024 blocks -> 4 blocks/CU, all resident

// workspace layout (floats):
//   vwT : [256][256] transpose of value_w   offset 0
//   qk  : [4][256]   folded query@key_w     offset 65536
//   qb  : [4]        folded query@key_b     offset 66560
#define WS_QK 65536
#define WS_QB (WS_QK + NH * DIM)

// ---------------------------------------------------------------------------
// Prep: transpose value_w (blocks 0..63), qk per head (blocks 64..67), qb (68)
// ---------------------------------------------------------------------------
__global__ __launch_bounds__(256) void prep_kernel(
    const float* __restrict__ query,
    const float* __restrict__ key_w,
    const float* __restrict__ key_b,
    const float* __restrict__ value_w,
    float* __restrict__ ws) {
  float* vwT = ws;
  float* qk  = ws + WS_QK;
  float* qb  = ws + WS_QB;
  const int t = threadIdx.x;

  if (blockIdx.x < 64) {
    __shared__ float tile[32][33];
    const int bx = (blockIdx.x & 7) * 32;
    const int by = (blockIdx.x >> 3) * 32;
    const int tx = t & 31, ty = t >> 5;
#pragma unroll
    for (int k = 0; k < 4; ++k)
      tile[ty + 8 * k][tx] = value_w[(by + ty + 8 * k) * DIM + bx + tx];
    __syncthreads();
#pragma unroll
    for (int k = 0; k < 4; ++k)
      vwT[(bx + ty + 8 * k) * DIM + by + tx] = tile[tx][ty + 8 * k];
  } else if (blockIdx.x < 68) {
    const int h = blockIdx.x - 64;  // one head per block
    float acc = 0.f;
#pragma unroll 8
    for (int d = 0; d < HD; ++d)
      acc += query[h * HD + d] * key_w[(h * HD + d) * DIM + t];
    qk[h * DIM + t] = acc * 0.125f;  // HD^-0.5
  } else {
    if (t < NH) {
      float acc = 0.f;
      for (int d = 0; d < HD; ++d)
        acc += query[t * HD + d] * key_b[t * HD + d];
      qb[t] = acc * 0.125f;
    }
  }
}

// Redistribute-reduce: from per-lane partials p0..p3 (heads 0..3), returns the
// 4-lane-group partial sum for head (l&3) in 3 shuffles. Caller finishes with
// butterfly xor 4,8,16,32 -> every lane holds the FULL sum for head (l&3).
__device__ __forceinline__ float head_partial(float p0, float p1, float p2,
                                              float p3, int l) {
  const bool odd = (l & 1) != 0;
  float sa = odd ? p0 : p1;            // send the head you don't keep
  float ra = __shfl_xor(sa, 1, 64);
  float vl = (odd ? p1 : p0) + ra;     // head (l&1), span 2 lanes
  float sb = odd ? p2 : p3;
  float rb = __shfl_xor(sb, 1, 64);
  float vh = (odd ? p3 : p2) + rb;     // head (l&1)+2, span 2 lanes
  const bool g2 = (l & 2) != 0;
  float sc = g2 ? vl : vh;
  float rc = __shfl_xor(sc, 2, 64);
  return (g2 ? vh : vl) + rc;          // head (l&3), span 4 lanes
}

// ---------------------------------------------------------------------------
// Main: 1024 blocks x 8 segments (2 per wave). Stream x once, 4 rows/iter.
// Accumulator slot j of lane l holds head (l&3)^j; un-permuted at LDS write.
// ---------------------------------------------------------------------------
__global__ __launch_bounds__(256) void main_kernel(
    const float* __restrict__ x,
    const int* __restrict__ batch,
    const float* __restrict__ value_b,
    const float* __restrict__ ws,
    float* __restrict__ out) {
  const float* vwT = ws;
  const float* qk  = ws + WS_QK;
  const float* qb  = ws + WS_QB;

  __shared__ float zu[SPB][NH][DIM];
  __shared__ float sSh[SPB][NH];
  __shared__ int   segb[SPB + 1];

  const int t = threadIdx.x;
  const int w = t >> 6;
  const int l = t & 63;

  // 9 threads each do one binary search (batch is sorted)
  if (t <= SPB) {
    const int target = blockIdx.x * SPB + t;
    int lo = 0, hi = NROWS;
    while (lo < hi) { int mid = (lo + hi) >> 1; if (batch[mid] < target) lo = mid + 1; else hi = mid; }
    segb[t] = lo;
  }
  __syncthreads();

  const int h4 = l & 3;
  const float4 q0 = *(const float4*)(qk + 0 * DIM + 4 * l);
  const float4 q1 = *(const float4*)(qk + 1 * DIM + 4 * l);
  const float4 q2 = *(const float4*)(qk + 2 * DIM + 4 * l);
  const float4 q3 = *(const float4*)(qk + 3 * DIM + 4 * l);
  const float qbv = qb[h4];

#pragma unroll
  for (int ss = 0; ss < 2; ++ss) {
    const int seg = 2 * w + ss;
    const int start = segb[seg], end = segb[seg + 1];
    float4 z0 = {0.f, 0.f, 0.f, 0.f}, z1 = z0, z2 = z0, z3 = z0;
    float s0 = 0.f, s1 = 0.f, s2 = 0.f, s3 = 0.f;
    const float* xp = x + (size_t)start * DIM + 4 * l;
    int n = start;

    for (; n + 4 <= end; n += 4, xp += 4 * DIM) {
      const float4 xv0 = *(const float4*)(xp);
      const float4 xv1 = *(const float4*)(xp + DIM);
      const float4 xv2 = *(const float4*)(xp + 2 * DIM);
      const float4 xv3 = *(const float4*)(xp + 3 * DIM);
      float v0, v1, v2, v3;
      {
        float p0 = q0.x * xv0.x + q0.y * xv0.y + q0.z * xv0.z + q0.w * xv0.w;
        float p1 = q1.x * xv0.x + q1.y * xv0.y + q1.z * xv0.z + q1.w * xv0.w;
        float p2 = q2.x * xv0.x + q2.y * xv0.y + q2.z * xv0.z + q2.w * xv0.w;
        float p3 = q3.x * xv0.x + q3.y * xv0.y + q3.z * xv0.z + q3.w * xv0.w;
        v0 = head_partial(p0, p1, p2, p3, l);
      }
      {
        float p0 = q0.x * xv1.x + q0.y * xv1.y + q0.z * xv1.z + q0.w * xv1.w;
        float p1 = q1.x * xv1.x + q1.y * xv1.y + q1.z * xv1.z + q1.w * xv1.w;
        float p2 = q2.x * xv1.x + q2.y * xv1.y + q2.z * xv1.z + q2.w * xv1.w;
        float p3 = q3.x * xv1.x + q3.y * xv1.y + q3.z * xv1.z + q3.w * xv1.w;
        v1 = head_partial(p0, p1, p2, p3, l);
      }
      {
        float p0 = q0.x * xv2.x + q0.y * xv2.y + q0.z * xv2.z + q0.w * xv2.w;
        float p1 = q1.x * xv2.x + q1.y * xv2.y + q1.z * xv2.z + q1.w * xv2.w;
        float p2 = q2.x * xv2.x + q2.y * xv2.y + q2.z * xv2.z + q2.w * xv2.w;
        float p3 = q3.x * xv2.x + q3.y * xv2.y + q3.z * xv2.z + q3.w * xv2.w;
        v2 = head_partial(p0, p1, p2, p3, l);
      }
      {
        float p0 = q0.x * xv3.x + q0.y * xv3.y + q0.z * xv3.z + q0.w * xv3.w;
        float p1 = q1.x * xv3.x + q1.y * xv3.y + q1.z * xv3.z + q1.w * xv3.w;
        float p2 = q2.x * xv3.x + q2.y * xv3.y + q2.z * xv3.z + q2.w * xv3.w;
        float p3 = q3.x * xv3.x + q3.y * xv3.y + q3.z * xv3.z + q3.w * xv3.w;
        v3 = head_partial(p0, p1, p2, p3, l);
      }
      // 4 independent butterfly chains, pipelined through the DS unit
#pragma unroll
      for (int m = 4; m <= 32; m <<= 1) {
        v0 += __shfl_xor(v0, m, 64);
        v1 += __shfl_xor(v1, m, 64);
        v2 += __shfl_xor(v2, m, 64);
        v3 += __shfl_xor(v3, m, 64);
      }
      const float e00 = __expf(fminf(fmaxf(v0 + qbv, -20.f), 20.f));
      const float e10 = __expf(fminf(fmaxf(v1 + qbv, -20.f), 20.f));
      const float e20 = __expf(fminf(fmaxf(v2 + qbv, -20.f), 20.f));
      const float e30 = __expf(fminf(fmaxf(v3 + qbv, -20.f), 20.f));
      const float e01 = __shfl_xor(e00, 1, 64), e02 = __shfl_xor(e00, 2, 64), e03 = __shfl_xor(e00, 3, 64);
      const float e11 = __shfl_xor(e10, 1, 64), e12 = __shfl_xor(e10, 2, 64), e13 = __shfl_xor(e10, 3, 64);
      const float e21 = __shfl_xor(e20, 1, 64), e22 = __shfl_xor(e20, 2, 64), e23 = __shfl_xor(e20, 3, 64);
      const float e31 = __shfl_xor(e30, 1, 64), e32 = __shfl_xor(e30, 2, 64), e33 = __shfl_xor(e30, 3, 64);
      s0 += e00 + e10 + e20 + e30;
      s1 += e01 + e11 + e21 + e31;
      s2 += e02 + e12 + e22 + e32;
      s3 += e03 + e13 + e23 + e33;
      z0.x += e00 * xv0.x + e10 * xv1.x + e20 * xv2.x + e30 * xv3.x;
      z0.y += e00 * xv0.y + e10 * xv1.y + e20 * xv2.y + e30 * xv3.y;
      z0.z += e00 * xv0.z + e10 * xv1.z + e20 * xv2.z + e30 * xv3.z;
      z0.w += e00 * xv0.w + e10 * xv1.w + e20 * xv2.w + e30 * xv3.w;
      z1.x += e01 * xv0.x + e11 * xv1.x + e21 * xv2.x + e31 * xv3.x;
      z1.y += e01 * xv0.y + e11 * xv1.y + e21 * xv2.y + e31 * xv3.y;
      z1.z += e01 * xv0.z + e11 * xv1.z + e21 * xv2.z + e31 * xv3.z;
      z1.w += e01 * xv0.w + e11 * xv1.w + e21 * xv2.w + e31 * xv3.w;
      z2.x += e02 * xv0.x + e12 * xv1.x + e22 * xv2.x + e32 * xv3.x;
      z2.y += e02 * xv0.y + e12 * xv1.y + e22 * xv2.y + e32 * xv3.y;
      z2.z += e02 * xv0.z + e12 * xv1.z + e22 * xv2.z + e32 * xv3.z;
      z2.w += e02 * xv0.w + e12 * xv1.w + e22 * xv2.w + e32 * xv3.w;
      z3.x += e03 * xv0.x + e13 * xv1.x + e23 * xv2.x + e33 * xv3.x;
      z3.y += e03 * xv0.y + e13 * xv1.y + e23 * xv2.y + e33 * xv3.y;
      z3.z += e03 * xv0.z + e13 * xv1.z + e23 * xv2.z + e33 * xv3.z;
      z3.w += e03 * xv0.w + e13 * xv1.w + e23 * xv2.w + e33 * xv3.w;
    }
    for (; n < end; ++n, xp += DIM) {
      const float4 xv = *(const float4*)(xp);
      float p0 = q0.x * xv.x + q0.y * xv.y + q0.z * xv.z + q0.w * xv.w;
      float p1 = q1.x * xv.x + q1.y * xv.y + q1.z * xv.z + q1.w * xv.w;
      float p2 = q2.x * xv.x + q2.y * xv.y + q2.z * xv.z + q2.w * xv.w;
      float p3 = q3.x * xv.x + q3.y * xv.y + q3.z * xv.z + q3.w * xv.w;
      float v = head_partial(p0, p1, p2, p3, l);
#pragma unroll
      for (int m = 4; m <= 32; m <<= 1) v += __shfl_xor(v, m, 64);
      const float e0 = __expf(fminf(fmaxf(v + qbv, -20.f), 20.f));
      const float e1 = __shfl_xor(e0, 1, 64);
      const float e2 = __shfl_xor(e0, 2, 64);
      const float e3 = __shfl_xor(e0, 3, 64);
      s0 += e0; s1 += e1; s2 += e2; s3 += e3;
      z0.x += e0 * xv.x; z0.y += e0 * xv.y; z0.z += e0 * xv.z; z0.w += e0 * xv.w;
      z1.x += e1 * xv.x; z1.y += e1 * xv.y; z1.z += e1 * xv.z; z1.w += e1 * xv.w;
      z2.x += e2 * xv.x; z2.y += e2 * xv.y; z2.z += e2 * xv.z; z2.w += e2 * xv.w;
      z3.x += e3 * xv.x; z3.y += e3 * xv.y; z3.z += e3 * xv.z; z3.w += e3 * xv.w;
    }
    // un-permute accumulator slots: slot j of lane l holds head (l&3)^j
    *(float4*)&zu[seg][h4 ^ 0][4 * l] = z0;
    *(float4*)&zu[seg][h4 ^ 1][4 * l] = z1;
    *(float4*)&zu[seg][h4 ^ 2][4 * l] = z2;
    *(float4*)&zu[seg][h4 ^ 3][4 * l] = z3;
    if (l == 0) { sSh[seg][0] = s0; sSh[seg][1] = s1; sSh[seg][2] = s2; sSh[seg][3] = s3; }
  }
  __syncthreads();

  // Epilogue: out[b, r] = z@vwT/(s+eps) + (s/(s+eps))*value_b ; thread t owns
  // output column r=t (head h=t>>6) for all 8 segments.
  const int h = t >> 6;
  float inv[SPB], cb[SPB];
#pragma unroll
  for (int seg = 0; seg < SPB; ++seg) {
    const float sv = sSh[seg][h];
    const float iv = 1.f / (sv + 1e-8f);
    inv[seg] = iv;
    cb[seg]  = sv * iv;
  }
  float acc[SPB];
#pragma unroll
  for (int seg = 0; seg < SPB; ++seg) acc[seg] = 0.f;
  for (int i = 0; i < DIM; i += 4) {
    const float w0 = vwT[(i + 0) * DIM + t];
    const float w1 = vwT[(i + 1) * DIM + t];
    const float w2 = vwT[(i + 2) * DIM + t];
    const float w3 = vwT[(i + 3) * DIM + t];
#pragma unroll
    for (int seg = 0; seg < SPB; ++seg) {
      const float4 zz = *(const float4*)&zu[seg][h][i];
      acc[seg] += w0 * zz.x + w1 * zz.y + w2 * zz.z + w3 * zz.w;
    }
  }
  const float vb = value_b[t];
  const int b0 = blockIdx.x * SPB;
#pragma unroll
  for (int seg = 0; seg < SPB; ++seg)
    out[(size_t)(b0 + seg) * DIM + t] = acc[seg] * inv[seg] + cb[seg] * vb;
}

extern "C" void kernel_launch(void* const* d_in, const int* in_sizes, int n_in,
                              void* d_out, int out_size, void* d_ws, size_t ws_size,
                              hipStream_t stream) {
  const float* x       = (const float*)d_in[0];
  const int*   batch   = (const int*)d_in[1];
  const float* query   = (const float*)d_in[2];
  const float* key_w   = (const float*)d_in[3];
  const float* key_b   = (const float*)d_in[4];
  const float* value_w = (const float*)d_in[5];
  const float* value_b = (const float*)d_in[6];
  float* out = (float*)d_out;
  float* ws  = (float*)d_ws;

  prep_kernel<<<69, 256, 0, stream>>>(query, key_w, key_b, value_w, ws);
  main_kernel<<<NBLK, 256, 0, stream>>>(x, batch, value_b, ws, out);
}